// Round 1
// baseline (552.786 us; speedup 1.0000x reference)
//
#include <hip/hip_runtime.h>
#include <math.h>
#include <float.h>

#define D_DIM 768
#define K_C   256
#define BM    64
#define CHUNK 32
#define NCHUNK (D_DIM/CHUNK)
#define MAXFIX 16384
#define MARGIN 3e-4f

// ---------------- prep: c2 in f64, zero fixup counter ----------------
__global__ void kprep(const float* __restrict__ C, float* __restrict__ c2f,
                      int* __restrict__ fix_cnt)
{
    int k = threadIdx.x;            // 256 threads, 1 block
    double s = 0.0;
    for (int d = 0; d < D_DIM; ++d) {
        double v = (double)C[(size_t)k*D_DIM + d];
        s += v*v;
    }
    c2f[k] = (float)s;
    if (k == 0) *fix_cnt = 0;
}

// merge helper semantics for (m, s1, s2) online-softmin partials:
// s1 = sum exp(m - d), s2 = sum d*exp(m - d) over the partial's elements.

// ---------------- main fused kernel ----------------
__global__ __launch_bounds__(256) void kdist(const float* __restrict__ E,
    const float* __restrict__ C, const float* __restrict__ c2,
    float* __restrict__ labels, float* __restrict__ partials,
    int* __restrict__ fix_cnt, int* __restrict__ fix_list)
{
    __shared__ float Elds[CHUNK][BM];       // [kk][row]   8 KB
    __shared__ float Clds[CHUNK][K_C];      // [kk][cent] 32 KB
    __shared__ float Wpart[4][K_C][3];      // per-wave partials 12 KB

    const int t  = threadIdx.x;
    const int tx = t & 15;          // column group (16 cols each)
    const int ty = t >> 4;          // row group (4 rows each)
    const int R0 = blockIdx.x * BM;

    float dot[4][16];
#pragma unroll
    for (int r = 0; r < 4; ++r)
#pragma unroll
        for (int j = 0; j < 16; ++j) dot[r][j] = 0.f;
    float e2[4] = {0.f, 0.f, 0.f, 0.f};

    for (int ch = 0; ch < NCHUNK; ++ch) {
        const int ck = ch * CHUNK;
        __syncthreads();
        // stage E tile (transposed into LDS), coalesced global reads
#pragma unroll
        for (int i = 0; i < 2; ++i) {
            int f = t + 256*i;
            int row = f >> 3, p = f & 7;
            float4 v = *reinterpret_cast<const float4*>(
                &E[(size_t)(R0+row)*D_DIM + ck + p*4]);
            Elds[p*4+0][row] = v.x;
            Elds[p*4+1][row] = v.y;
            Elds[p*4+2][row] = v.z;
            Elds[p*4+3][row] = v.w;
        }
        // stage centroid tile (transposed)
#pragma unroll
        for (int i = 0; i < 8; ++i) {
            int f = t + 256*i;
            int kr = f >> 3, p = f & 7;
            float4 v = *reinterpret_cast<const float4*>(
                &C[(size_t)kr*D_DIM + ck + p*4]);
            Clds[p*4+0][kr] = v.x;
            Clds[p*4+1][kr] = v.y;
            Clds[p*4+2][kr] = v.z;
            Clds[p*4+3][kr] = v.w;
        }
        __syncthreads();
#pragma unroll 4
        for (int kk = 0; kk < CHUNK; ++kk) {
            float4 ev = *reinterpret_cast<const float4*>(&Elds[kk][ty*4]);
            float cv[16];
#pragma unroll
            for (int q = 0; q < 4; ++q) {
                float4 c4 = *reinterpret_cast<const float4*>(&Clds[kk][tx*16 + q*4]);
                cv[q*4+0]=c4.x; cv[q*4+1]=c4.y; cv[q*4+2]=c4.z; cv[q*4+3]=c4.w;
            }
            float er[4] = {ev.x, ev.y, ev.z, ev.w};
#pragma unroll
            for (int r = 0; r < 4; ++r) {
                e2[r] = fmaf(er[r], er[r], e2[r]);
#pragma unroll
                for (int j = 0; j < 16; ++j)
                    dot[r][j] = fmaf(er[r], cv[j], dot[r][j]);
            }
        }
    }

    // distances (overwrite dot[][] with dist to save VGPRs)
    float c2v[16];
#pragma unroll
    for (int j = 0; j < 16; ++j) c2v[j] = c2[tx*16 + j];
#pragma unroll
    for (int r = 0; r < 4; ++r)
#pragma unroll
        for (int j = 0; j < 16; ++j) {
            float d2 = fmaf(-2.f, dot[r][j], e2[r] + c2v[j]);
            dot[r][j] = sqrtf(fmaxf(d2, 0.f));
        }

    // ---- argmin (track top-2) per row; first-index tie semantics ----
#pragma unroll
    for (int r = 0; r < 4; ++r) {
        float v1 = FLT_MAX, v2 = FLT_MAX;
        int i1 = 0x7fffffff, i2 = 0x7fffffff;
#pragma unroll
        for (int j = 0; j < 16; ++j) {
            float v = dot[r][j]; int idx = tx*16 + j;
            if (v < v1)      { v2 = v1; i2 = i1; v1 = v; i1 = idx; }
            else if (v < v2) { v2 = v; i2 = idx; }
        }
        for (int m = 1; m < 16; m <<= 1) {
            float b1 = __shfl_xor(v1, m, 64); int bi1 = __shfl_xor(i1, m, 64);
            float b2 = __shfl_xor(v2, m, 64); int bi2 = __shfl_xor(i2, m, 64);
            bool afirst = (v1 < b1) || (v1 == b1 && i1 < bi1);
            float n1, n2; int ni1, ni2;
            if (afirst) {
                n1 = v1; ni1 = i1;
                bool s = (v2 < b1) || (v2 == b1 && i2 < bi1);
                n2 = s ? v2 : b1; ni2 = s ? i2 : bi1;
            } else {
                n1 = b1; ni1 = bi1;
                bool s = (b2 < v1) || (b2 == v1 && bi2 < i1);
                n2 = s ? b2 : v1; ni2 = s ? bi2 : i1;
            }
            v1 = n1; i1 = ni1; v2 = n2; i2 = ni2;
        }
        if (tx == 0) {
            int row = R0 + ty*4 + r;
            labels[row] = (float)i1;
            if (v2 - v1 < MARGIN) {              // near-tie -> f64 refinement
                int slot = atomicAdd(fix_cnt, 1);
                if (slot < MAXFIX) {
                    fix_list[slot*3+0] = row;
                    fix_list[slot*3+1] = i1;
                    fix_list[slot*3+2] = i2;
                }
            }
        }
    }

    // ---- per-centroid softmin partials (min, s1, s2) over this block's rows ----
    float mcol[16], s1[16], s2[16];
#pragma unroll
    for (int j = 0; j < 16; ++j) {
        float m0 = fminf(fminf(dot[0][j], dot[1][j]), fminf(dot[2][j], dot[3][j]));
        float a = 0.f, b = 0.f;
#pragma unroll
        for (int r = 0; r < 4; ++r) {
            float w = expf(m0 - dot[r][j]);
            a += w; b += dot[r][j]*w;
        }
        mcol[j] = m0; s1[j] = a; s2[j] = b;
    }
    // combine the 4 row-groups resident in this wave (lanes stride 16)
#pragma unroll
    for (int msk = 16; msk < 64; msk <<= 1) {
#pragma unroll
        for (int j = 0; j < 16; ++j) {
            float om = __shfl_xor(mcol[j], msk, 64);
            float oa = __shfl_xor(s1[j], msk, 64);
            float ob = __shfl_xor(s2[j], msk, 64);
            float M  = fminf(mcol[j], om);
            float sa = expf(M - mcol[j]);
            float sb = expf(M - om);
            s1[j] = s1[j]*sa + oa*sb;
            s2[j] = s2[j]*sa + ob*sb;
            mcol[j] = M;
        }
    }
    const int wv = t >> 6;
    if ((ty & 3) == 0) {
#pragma unroll
        for (int j = 0; j < 16; ++j) {
            int c = tx*16 + j;
            Wpart[wv][c][0] = mcol[j];
            Wpart[wv][c][1] = s1[j];
            Wpart[wv][c][2] = s2[j];
        }
    }
    __syncthreads();
    {   // one thread per centroid merges the 4 wave partials
        int c = t;
        float M = Wpart[0][c][0], A = Wpart[0][c][1], Bv = Wpart[0][c][2];
#pragma unroll
        for (int i = 1; i < 4; ++i) {
            float om = Wpart[i][c][0], oa = Wpart[i][c][1], ob = Wpart[i][c][2];
            float Mn = fminf(M, om);
            float sa = expf(Mn - M), sb = expf(Mn - om);
            A = A*sa + oa*sb; Bv = Bv*sa + ob*sb; M = Mn;
        }
        float* p = &partials[((size_t)blockIdx.x*K_C + c)*3];
        p[0] = M; p[1] = A; p[2] = Bv;
    }
}

// ---------------- f64 refinement of near-tie argmin rows ----------------
__global__ __launch_bounds__(256) void krefine(const float* __restrict__ E,
    const float* __restrict__ C, const int* __restrict__ fix_cnt,
    const int* __restrict__ fix_list, float* __restrict__ labels)
{
    int cnt = *fix_cnt; if (cnt > MAXFIX) cnt = MAXFIX;
    int lane = threadIdx.x & 63;
    int wv = (int)((blockIdx.x * blockDim.x + threadIdx.x) >> 6);
    const int NW = (gridDim.x * blockDim.x) >> 6;
    for (int e = wv; e < cnt; e += NW) {
        int row = fix_list[e*3+0], k1 = fix_list[e*3+1], k2 = fix_list[e*3+2];
        double d1 = 0, d2 = 0, q1 = 0, q2 = 0;
        for (int d = lane; d < D_DIM; d += 64) {
            double ed = (double)E[(size_t)row*D_DIM + d];
            double ca = (double)C[(size_t)k1*D_DIM + d];
            double cb = (double)C[(size_t)k2*D_DIM + d];
            d1 += ed*ca; q1 += ca*ca;
            d2 += ed*cb; q2 += cb*cb;
        }
#pragma unroll
        for (int msk = 32; msk; msk >>= 1) {
            d1 += __shfl_down(d1, msk, 64);
            d2 += __shfl_down(d2, msk, 64);
            q1 += __shfl_down(q1, msk, 64);
            q2 += __shfl_down(q2, msk, 64);
        }
        if (lane == 0) {
            double val1 = q1 - 2.0*d1, val2 = q2 - 2.0*d2;   // e2 cancels
            int lab = (val2 < val1 || (val2 == val1 && k2 < k1)) ? k2 : k1;
            labels[row] = (float)lab;
        }
    }
}

// ---------------- per-centroid global combine ----------------
__global__ __launch_bounds__(256) void kcol(const float* __restrict__ partials,
                                            float* __restrict__ colloss, int NB)
{
    __shared__ float Wm[4], Wa[4], Wb[4];
    const int c = blockIdx.x;
    const int t = threadIdx.x;
    float M = FLT_MAX, A = 0.f, Bv = 0.f;
    for (int b = t; b < NB; b += 256) {
        const float* p = &partials[((size_t)b*K_C + c)*3];
        float om = p[0], oa = p[1], ob = p[2];
        float Mn = fminf(M, om);
        float sa = expf(Mn - M), sb = expf(Mn - om);
        A = A*sa + oa*sb; Bv = Bv*sa + ob*sb; M = Mn;
    }
    for (int msk = 1; msk < 64; msk <<= 1) {
        float om = __shfl_xor(M, msk, 64);
        float oa = __shfl_xor(A, msk, 64);
        float ob = __shfl_xor(Bv, msk, 64);
        float Mn = fminf(M, om);
        float sa = expf(Mn - M), sb = expf(Mn - om);
        A = A*sa + oa*sb; Bv = Bv*sa + ob*sb; M = Mn;
    }
    int lane = t & 63, w = t >> 6;
    if (lane == 0) { Wm[w] = M; Wa[w] = A; Wb[w] = Bv; }
    __syncthreads();
    if (t == 0) {
#pragma unroll
        for (int i = 1; i < 4; ++i) {
            float om = Wm[i], oa = Wa[i], ob = Wb[i];
            float Mn = fminf(M, om);
            float sa = expf(Mn - M), sb = expf(Mn - om);
            A = A*sa + oa*sb; Bv = Bv*sa + ob*sb; M = Mn;
        }
        colloss[c] = Bv / A;
    }
}

// ---------------- final mean over centroids ----------------
__global__ __launch_bounds__(256) void kfinal(const float* __restrict__ colloss,
                                              float* __restrict__ out)
{
    __shared__ float Ws[4];
    int t = threadIdx.x;
    float v = colloss[t];
    for (int msk = 1; msk < 64; msk <<= 1) v += __shfl_xor(v, msk, 64);
    if ((t & 63) == 0) Ws[t >> 6] = v;
    __syncthreads();
    if (t == 0) out[0] = (Ws[0] + Ws[1] + Ws[2] + Ws[3]) / 256.0f;
}

extern "C" void kernel_launch(void* const* d_in, const int* in_sizes, int n_in,
                              void* d_out, int out_size, void* d_ws, size_t ws_size,
                              hipStream_t stream)
{
    const float* E = (const float*)d_in[0];
    const float* C = (const float*)d_in[1];
    float* out = (float*)d_out;

    const int Bn = in_sizes[0] / D_DIM;      // 65536
    const int NB = Bn / BM;                  // 1024

    float* c2f      = (float*)d_ws;
    int*   fix_cnt  = (int*)((char*)d_ws + 1024);
    int*   fix_list = (int*)((char*)d_ws + 1088);
    float* partials = (float*)((char*)d_ws + 1088 + MAXFIX*12);
    float* colloss  = partials + (size_t)NB * K_C * 3;
    float* labels   = out + 1;

    kprep  <<<1,   256, 0, stream>>>(C, c2f, fix_cnt);
    kdist  <<<NB,  256, 0, stream>>>(E, C, c2f, labels, partials, fix_cnt, fix_list);
    krefine<<<64,  256, 0, stream>>>(E, C, fix_cnt, fix_list, labels);
    kcol   <<<K_C, 256, 0, stream>>>(partials, colloss, NB);
    kfinal <<<1,   256, 0, stream>>>(colloss, out);
}

// Round 2
// 146.643 us; speedup vs baseline: 3.7696x; 3.7696x over previous
//
#include <hip/hip_runtime.h>
#include <math.h>
#include <float.h>

#define D_DIM 768
#define K_C   256
#define BM    128
#define KC    32
#define NCH   (D_DIM/KC)       // 24
#define BPAD  40               // padded LDS row (elems) -> 80B, breaks bank stride
#define MAXFIX 16384
#define MARGIN 1e-3f

typedef __attribute__((ext_vector_type(8))) short s16x8;
typedef __attribute__((ext_vector_type(4))) float f32x4;

__device__ inline unsigned short f2bf(float x) {      // RNE f32 -> bf16 bits
    unsigned u = __float_as_uint(x);
    unsigned r = 0x7FFFu + ((u >> 16) & 1u);
    return (unsigned short)((u + r) >> 16);
}
__device__ inline float bf2f(unsigned short h) {
    return __uint_as_float(((unsigned)h) << 16);
}

// ---------------- prep: C -> chunk-major bf16 hi/lo, c2 in f64 ----------------
__global__ __launch_bounds__(256) void kprep(const float* __restrict__ C,
    short* __restrict__ Chik, short* __restrict__ Clok,
    float* __restrict__ c2f, int* __restrict__ fix_cnt)
{
    const int k = blockIdx.x;      // centroid
    const int t = threadIdx.x;
    __shared__ double red[4];
    double s = 0.0;
    for (int d = t; d < D_DIM; d += 256) {
        float x = C[(size_t)k*D_DIM + d];
        unsigned short h = f2bf(x);
        unsigned short l = f2bf(x - bf2f(h));
        int ch = d >> 5, kk = d & 31;
        size_t o = ((size_t)ch*K_C + k)*KC + kk;
        Chik[o] = (short)h;
        Clok[o] = (short)l;
        s += (double)x * (double)x;
    }
#pragma unroll
    for (int m = 1; m < 64; m <<= 1) s += __shfl_xor(s, m, 64);
    if ((t & 63) == 0) red[t >> 6] = s;
    __syncthreads();
    if (t == 0) {
        c2f[k] = (float)(red[0] + red[1] + red[2] + red[3]);
        if (k == 0) *fix_cnt = 0;
    }
}

// ---------------- main fused MFMA kernel ----------------
__global__ __launch_bounds__(256, 2) void kdist(const float* __restrict__ E,
    const short* __restrict__ Chik, const short* __restrict__ Clok,
    const float* __restrict__ c2f, float* __restrict__ labels,
    float* __restrict__ partials, int* __restrict__ fix_cnt,
    int* __restrict__ fix_list)
{
    __shared__ short EhiL[BM*BPAD], EloL[BM*BPAD];      // 10 KB each
    __shared__ short ChiL[K_C*BPAD], CloL[K_C*BPAD];    // 20 KB each
    __shared__ float e2s[BM];
    __shared__ float spart[2][K_C][3];
    __shared__ float4 topb[2][BM];

    const int t    = threadIdx.x;
    const int lane = t & 63;
    const int w    = t >> 6;
    const int wm   = w >> 1, wn = w & 1;
    const int c4   = lane & 15, sgr = lane >> 4;
    const int R0   = blockIdx.x * BM;

    f32x4 acc[4][8];
#pragma unroll
    for (int m = 0; m < 4; ++m)
#pragma unroll
        for (int n = 0; n < 8; ++n) acc[m][n] = (f32x4){0.f,0.f,0.f,0.f};

    const int srow = t >> 1, sseg = t & 1;
    const float* Esrc = E + (size_t)(R0 + srow)*D_DIM + sseg*16;
    short* Ehdst = &EhiL[srow*BPAD + sseg*16];
    short* Eldst = &EloL[srow*BPAD + sseg*16];
    short* Chdst = &ChiL[t*BPAD];
    short* Cldst = &CloL[t*BPAD];

    float e2p = 0.f;

    for (int ch = 0; ch < NCH; ++ch) {
        __syncthreads();
        // ---- stage E (convert f32 -> bf16 hi/lo on the fly, accumulate e2) ----
        {
            const float* ep = Esrc + ch*KC;
            float xs[16];
            float4 v0 = *reinterpret_cast<const float4*>(ep);
            float4 v1 = *reinterpret_cast<const float4*>(ep+4);
            float4 v2 = *reinterpret_cast<const float4*>(ep+8);
            float4 v3 = *reinterpret_cast<const float4*>(ep+12);
            xs[0]=v0.x; xs[1]=v0.y; xs[2]=v0.z; xs[3]=v0.w;
            xs[4]=v1.x; xs[5]=v1.y; xs[6]=v1.z; xs[7]=v1.w;
            xs[8]=v2.x; xs[9]=v2.y; xs[10]=v2.z; xs[11]=v2.w;
            xs[12]=v3.x; xs[13]=v3.y; xs[14]=v3.z; xs[15]=v3.w;
            s16x8 H[2], L[2];
#pragma unroll
            for (int i = 0; i < 16; ++i) {
                float x = xs[i];
                e2p = fmaf(x, x, e2p);
                unsigned short h = f2bf(x);
                unsigned short l = f2bf(x - bf2f(h));
                H[i>>3][i&7] = (short)h;
                L[i>>3][i&7] = (short)l;
            }
            *reinterpret_cast<s16x8*>(Ehdst)   = H[0];
            *reinterpret_cast<s16x8*>(Ehdst+8) = H[1];
            *reinterpret_cast<s16x8*>(Eldst)   = L[0];
            *reinterpret_cast<s16x8*>(Eldst+8) = L[1];
        }
        // ---- stage C (pre-converted, chunk-major -> coalesced) ----
        {
            const short* cs = Chik + ((size_t)ch*K_C + t)*KC;
            const short* ls = Clok + ((size_t)ch*K_C + t)*KC;
#pragma unroll
            for (int q = 0; q < 4; ++q) {
                *reinterpret_cast<s16x8*>(Chdst + q*8) =
                    *reinterpret_cast<const s16x8*>(cs + q*8);
                *reinterpret_cast<s16x8*>(Cldst + q*8) =
                    *reinterpret_cast<const s16x8*>(ls + q*8);
            }
        }
        __syncthreads();

        // ---- MFMA: acc += Ehi*Chi + Elo*Chi + Ehi*Clo ----
        const int ks = sgr*8;
        s16x8 ahi[4], alo[4];
#pragma unroll
        for (int m = 0; m < 4; ++m) {
            int r = wm*64 + m*16 + c4;
            ahi[m] = *reinterpret_cast<const s16x8*>(&EhiL[r*BPAD + ks]);
            alo[m] = *reinterpret_cast<const s16x8*>(&EloL[r*BPAD + ks]);
        }
#pragma unroll
        for (int n = 0; n < 8; ++n) {
            int cc = wn*128 + n*16 + c4;
            s16x8 bhi = *reinterpret_cast<const s16x8*>(&ChiL[cc*BPAD + ks]);
            s16x8 blo = *reinterpret_cast<const s16x8*>(&CloL[cc*BPAD + ks]);
#pragma unroll
            for (int m = 0; m < 4; ++m) {
                acc[m][n] = __builtin_amdgcn_mfma_f32_16x16x32_bf16(ahi[m], bhi, acc[m][n], 0, 0, 0);
                acc[m][n] = __builtin_amdgcn_mfma_f32_16x16x32_bf16(alo[m], bhi, acc[m][n], 0, 0, 0);
                acc[m][n] = __builtin_amdgcn_mfma_f32_16x16x32_bf16(ahi[m], blo, acc[m][n], 0, 0, 0);
            }
        }
    }

    // ---- finish e2 per row ----
    {
        float o = __shfl_xor(e2p, 1, 64);
        if ((t & 1) == 0) e2s[t >> 1] = e2p + o;
    }
    __syncthreads();

    float e2r[4][4];
#pragma unroll
    for (int m = 0; m < 4; ++m)
#pragma unroll
        for (int g = 0; g < 4; ++g)
            e2r[m][g] = e2s[wm*64 + m*16 + sgr*4 + g];
    float c2v[8];
#pragma unroll
    for (int n = 0; n < 8; ++n) c2v[n] = c2f[wn*128 + n*16 + c4];

    // ---- dot -> dist (C/D layout: col=lane&15, row=(lane>>4)*4+reg) ----
#pragma unroll
    for (int m = 0; m < 4; ++m)
#pragma unroll
        for (int n = 0; n < 8; ++n) {
            f32x4 v = acc[m][n];
#pragma unroll
            for (int g = 0; g < 4; ++g) {
                float d2 = fmaf(-2.f, v[g], e2r[m][g] + c2v[n]);
                v[g] = sqrtf(fmaxf(d2, 0.f));
            }
            acc[m][n] = v;
        }

    // ---- top-2 argmin per row over this wave's 128 cols ----
#pragma unroll
    for (int m = 0; m < 4; ++m)
#pragma unroll
        for (int g = 0; g < 4; ++g) {
            float v1 = FLT_MAX, v2 = FLT_MAX;
            int i1 = 0x7fffffff, i2 = 0x7fffffff;
#pragma unroll
            for (int n = 0; n < 8; ++n) {
                float d = acc[m][n][g];
                int idx = wn*128 + n*16 + c4;
                if (d < v1)      { v2 = v1; i2 = i1; v1 = d; i1 = idx; }
                else if (d < v2) { v2 = d; i2 = idx; }
            }
#pragma unroll
            for (int msk = 1; msk < 16; msk <<= 1) {
                float b1 = __shfl_xor(v1, msk, 64); int bi1 = __shfl_xor(i1, msk, 64);
                float b2 = __shfl_xor(v2, msk, 64); int bi2 = __shfl_xor(i2, msk, 64);
                bool afirst = (v1 < b1) || (v1 == b1 && i1 < bi1);
                float n1, n2; int ni1, ni2;
                if (afirst) {
                    n1 = v1; ni1 = i1;
                    bool s = (v2 < b1) || (v2 == b1 && i2 < bi1);
                    n2 = s ? v2 : b1; ni2 = s ? i2 : bi1;
                } else {
                    n1 = b1; ni1 = bi1;
                    bool s = (b2 < v1) || (b2 == v1 && bi2 < i1);
                    n2 = s ? b2 : v1; ni2 = s ? bi2 : i1;
                }
                v1 = n1; i1 = ni1; v2 = n2; i2 = ni2;
            }
            if (c4 == 0) {
                float4 r; r.x = v1; r.y = (float)i1; r.z = v2; r.w = (float)i2;
                topb[wn][wm*64 + m*16 + sgr*4 + g] = r;
            }
        }

    // ---- per-centroid softmin partials over this wave's 64 rows ----
#pragma unroll
    for (int n = 0; n < 8; ++n) {
        float m0 = FLT_MAX;
#pragma unroll
        for (int m = 0; m < 4; ++m)
#pragma unroll
            for (int g = 0; g < 4; ++g) m0 = fminf(m0, acc[m][n][g]);
        float s1 = 0.f, s2 = 0.f;
#pragma unroll
        for (int m = 0; m < 4; ++m)
#pragma unroll
            for (int g = 0; g < 4; ++g) {
                float d = acc[m][n][g];
                float e = expf(m0 - d);
                s1 += e; s2 = fmaf(d, e, s2);
            }
#pragma unroll
        for (int msk = 16; msk < 64; msk <<= 1) {
            float om = __shfl_xor(m0, msk, 64);
            float oa = __shfl_xor(s1, msk, 64);
            float ob = __shfl_xor(s2, msk, 64);
            float Mn = fminf(m0, om);
            float sa = expf(Mn - m0), sb = expf(Mn - om);
            s1 = s1*sa + oa*sb;
            s2 = s2*sa + ob*sb;
            m0 = Mn;
        }
        if (lane < 16) {
            int cc = wn*128 + n*16 + c4;
            spart[wm][cc][0] = m0; spart[wm][cc][1] = s1; spart[wm][cc][2] = s2;
        }
    }
    __syncthreads();

    // ---- merges ----
    if (t < BM) {
        float4 a = topb[0][t], b = topb[1][t];
        float v1, v2; int i1, i2;
        if (a.x <= b.x) {
            v1 = a.x; i1 = (int)a.y;
            bool s = (a.z <= b.x);
            v2 = s ? a.z : b.x; i2 = s ? (int)a.w : (int)b.y;
        } else {
            v1 = b.x; i1 = (int)b.y;
            bool s = (a.x <= b.z);
            v2 = s ? a.x : b.z; i2 = s ? (int)a.y : (int)b.w;
        }
        int row = R0 + t;
        labels[row] = (float)i1;
        if (v2 - v1 < MARGIN) {
            int slot = atomicAdd(fix_cnt, 1);
            if (slot < MAXFIX) {
                fix_list[slot*3+0] = row;
                fix_list[slot*3+1] = i1;
                fix_list[slot*3+2] = i2;
            }
        }
    }
    {
        int cc = t;
        float M = spart[0][cc][0], A = spart[0][cc][1], Bv = spart[0][cc][2];
        float om = spart[1][cc][0], oa = spart[1][cc][1], ob = spart[1][cc][2];
        float Mn = fminf(M, om);
        float sa = expf(Mn - M), sb = expf(Mn - om);
        A = A*sa + oa*sb; Bv = Bv*sa + ob*sb;
        float* p = &partials[((size_t)blockIdx.x*K_C + cc)*3];
        p[0] = Mn; p[1] = A; p[2] = Bv;
    }
}

// ---------------- f64 refinement of near-tie argmin rows ----------------
__global__ __launch_bounds__(256) void krefine(const float* __restrict__ E,
    const float* __restrict__ C, const int* __restrict__ fix_cnt,
    const int* __restrict__ fix_list, float* __restrict__ labels)
{
    int cnt = *fix_cnt; if (cnt > MAXFIX) cnt = MAXFIX;
    int lane = threadIdx.x & 63;
    int wv = (int)((blockIdx.x * blockDim.x + threadIdx.x) >> 6);
    const int NW = (gridDim.x * blockDim.x) >> 6;
    for (int e = wv; e < cnt; e += NW) {
        int row = fix_list[e*3+0], k1 = fix_list[e*3+1], k2 = fix_list[e*3+2];
        double d1 = 0, d2 = 0, q1 = 0, q2 = 0;
        for (int d = lane; d < D_DIM; d += 64) {
            double ed = (double)E[(size_t)row*D_DIM + d];
            double ca = (double)C[(size_t)k1*D_DIM + d];
            double cb = (double)C[(size_t)k2*D_DIM + d];
            d1 += ed*ca; q1 += ca*ca;
            d2 += ed*cb; q2 += cb*cb;
        }
#pragma unroll
        for (int msk = 32; msk; msk >>= 1) {
            d1 += __shfl_down(d1, msk, 64);
            d2 += __shfl_down(d2, msk, 64);
            q1 += __shfl_down(q1, msk, 64);
            q2 += __shfl_down(q2, msk, 64);
        }
        if (lane == 0) {
            double val1 = q1 - 2.0*d1, val2 = q2 - 2.0*d2;   // e2 cancels
            int lab = (val2 < val1 || (val2 == val1 && k2 < k1)) ? k2 : k1;
            labels[row] = (float)lab;
        }
    }
}

// ---------------- per-centroid global combine ----------------
__global__ __launch_bounds__(256) void kcol(const float* __restrict__ partials,
                                            float* __restrict__ colloss, int NB)
{
    __shared__ float Wm[4], Wa[4], Wb[4];
    const int c = blockIdx.x;
    const int t = threadIdx.x;
    float M = FLT_MAX, A = 0.f, Bv = 0.f;
    for (int b = t; b < NB; b += 256) {
        const float* p = &partials[((size_t)b*K_C + c)*3];
        float om = p[0], oa = p[1], ob = p[2];
        float Mn = fminf(M, om);
        float sa = expf(Mn - M), sb = expf(Mn - om);
        A = A*sa + oa*sb; Bv = Bv*sa + ob*sb; M = Mn;
    }
    for (int msk = 1; msk < 64; msk <<= 1) {
        float om = __shfl_xor(M, msk, 64);
        float oa = __shfl_xor(A, msk, 64);
        float ob = __shfl_xor(Bv, msk, 64);
        float Mn = fminf(M, om);
        float sa = expf(Mn - M), sb = expf(Mn - om);
        A = A*sa + oa*sb; Bv = Bv*sa + ob*sb; M = Mn;
    }
    int lane = t & 63, wv = t >> 6;
    if (lane == 0) { Wm[wv] = M; Wa[wv] = A; Wb[wv] = Bv; }
    __syncthreads();
    if (t == 0) {
#pragma unroll
        for (int i = 1; i < 4; ++i) {
            float om = Wm[i], oa = Wa[i], ob = Wb[i];
            float Mn = fminf(M, om);
            float sa = expf(Mn - M), sb = expf(Mn - om);
            A = A*sa + oa*sb; Bv = Bv*sa + ob*sb; M = Mn;
        }
        colloss[c] = Bv / A;
    }
}

// ---------------- final mean over centroids ----------------
__global__ __launch_bounds__(256) void kfinal(const float* __restrict__ colloss,
                                              float* __restrict__ out)
{
    __shared__ float Ws[4];
    int t = threadIdx.x;
    float v = colloss[t];
    for (int msk = 1; msk < 64; msk <<= 1) v += __shfl_xor(v, msk, 64);
    if ((t & 63) == 0) Ws[t >> 6] = v;
    __syncthreads();
    if (t == 0) out[0] = (Ws[0] + Ws[1] + Ws[2] + Ws[3]) / 256.0f;
}

extern "C" void kernel_launch(void* const* d_in, const int* in_sizes, int n_in,
                              void* d_out, int out_size, void* d_ws, size_t ws_size,
                              hipStream_t stream)
{
    const float* E = (const float*)d_in[0];
    const float* C = (const float*)d_in[1];
    float* out = (float*)d_out;

    const int Bn = in_sizes[0] / D_DIM;      // 65536
    const int NB = Bn / BM;                  // 512

    char* ws = (char*)d_ws;
    float* c2f      = (float*)ws;                                  // 1 KB
    int*   fix_cnt  = (int*)(ws + 1024);
    int*   fix_list = (int*)(ws + 1088);                           // MAXFIX*12
    short* Chik     = (short*)(ws + 1088 + MAXFIX*12);             // 384 KB
    short* Clok     = Chik + (size_t)NCH*K_C*KC;                   // 384 KB
    float* partials = (float*)(Clok + (size_t)NCH*K_C*KC);         // NB*256*3*4
    float* colloss  = partials + (size_t)NB*K_C*3;
    float* labels   = out + 1;

    kprep  <<<K_C, 256, 0, stream>>>(C, Chik, Clok, c2f, fix_cnt);
    kdist  <<<NB,  256, 0, stream>>>(E, Chik, Clok, c2f, labels, partials,
                                     fix_cnt, fix_list);
    krefine<<<64,  256, 0, stream>>>(E, C, fix_cnt, fix_list, labels);
    kcol   <<<K_C, 256, 0, stream>>>(partials, colloss, NB);
    kfinal <<<1,   256, 0, stream>>>(colloss, out);
}